// Round 2
// baseline (2728.772 us; speedup 1.0000x reference)
//
#include <hip/hip_runtime.h>
#include <hip/hip_bf16.h>
#include <math.h>

#define B_SZ 4
#define SEQ  1024
#define DM   1024
#define DI   2048
#define DTR  64
#define DS   16
#define NTOK (B_SZ*SEQ)   /* 4096 tokens */

__device__ __forceinline__ float silu_f(float x) { return x / (1.f + __expf(-x)); }
__device__ __forceinline__ float softplus_f(float x) {
    return fmaxf(x, 0.f) + log1pf(__expf(-fabsf(x)));
}

// ---------------- LayerNorm over last dim (1024) ----------------
__global__ __launch_bounds__(256) void ln_kernel(const float* __restrict__ x,
                                                 const float* __restrict__ g,
                                                 const float* __restrict__ be,
                                                 float* __restrict__ xn) {
    int row = blockIdx.x;                      // token index 0..4095
    const float* xr = x + (long)row * DM;
    float v[4];
    float s = 0.f, ss = 0.f;
#pragma unroll
    for (int i = 0; i < 4; ++i) {
        v[i] = xr[threadIdx.x + 256 * i];
        s += v[i];
        ss += v[i] * v[i];
    }
#pragma unroll
    for (int off = 32; off >= 1; off >>= 1) {
        s  += __shfl_xor(s, off, 64);
        ss += __shfl_xor(ss, off, 64);
    }
    __shared__ float sh[8];
    int wid = threadIdx.x >> 6;
    if ((threadIdx.x & 63) == 0) { sh[wid] = s; sh[4 + wid] = ss; }
    __syncthreads();
    s  = sh[0] + sh[1] + sh[2] + sh[3];
    ss = sh[4] + sh[5] + sh[6] + sh[7];
    float mu  = s / DM;
    float var = ss / DM - mu * mu;             // population variance (jnp.var default)
    float rs  = rsqrtf(var + 1e-5f);
    float* xo = xn + (long)row * DM;
#pragma unroll
    for (int i = 0; i < 4; ++i) {
        int c = threadIdx.x + 256 * i;
        xo[c] = (v[i] - mu) * rs * g[c] + be[c];
    }
}

// ---------------- Generic fp32 GEMM:  C[m,n] = sum_k A[m,k]*B[n,k]  ----------------
// A: (M x K) row-major stride lda ; B: (N x K) row-major stride ldb (weight layout).
// M assumed multiple of 64 (always 4096 here). N may be ragged (masked).
// EPI: 0 = none, 1 = +bias, 2 = softplus(acc+bias), 3 = +bias +resid
template <int EPI>
__global__ __launch_bounds__(256) void gemm_nt(const float* __restrict__ A, int lda,
                                               const float* __restrict__ B, int ldb,
                                               float* __restrict__ C, int ldc,
                                               int N, int K,
                                               const float* __restrict__ bias,
                                               const float* __restrict__ resid, int ldr) {
    __shared__ __align__(16) float As[16][68];   // [k][m], +4 pad keeps 16B-aligned rows
    __shared__ __align__(16) float Bs[16][68];   // [k][n]
    const int tid = threadIdx.x;
    const int m0  = blockIdx.x * 64;
    const int n0  = blockIdx.y * 64;
    const int lr  = tid >> 2;          // 0..63 row of tile being loaded
    const int lc  = (tid & 3) << 2;    // 0,4,8,12 k-offset (float4)
    const int ty  = tid >> 4;          // 0..15
    const int tx  = tid & 15;          // 0..15
    float acc[4][4] = {};
    const float* ap0 = A + (long)(m0 + lr) * lda + lc;
    const float* bp0 = B + (long)(n0 + lr) * ldb + lc;
    const bool bvalid = (n0 + lr) < N;
    for (int k0 = 0; k0 < K; k0 += 16) {
        float4 av = *(const float4*)(ap0 + k0);
        float4 bv = make_float4(0.f, 0.f, 0.f, 0.f);
        if (bvalid) bv = *(const float4*)(bp0 + k0);
        __syncthreads();
        As[lc + 0][lr] = av.x; As[lc + 1][lr] = av.y; As[lc + 2][lr] = av.z; As[lc + 3][lr] = av.w;
        Bs[lc + 0][lr] = bv.x; Bs[lc + 1][lr] = bv.y; Bs[lc + 2][lr] = bv.z; Bs[lc + 3][lr] = bv.w;
        __syncthreads();
#pragma unroll
        for (int kk = 0; kk < 16; ++kk) {
            float4 a4 = *(const float4*)&As[kk][ty << 2];
            float4 b4 = *(const float4*)&Bs[kk][tx << 2];
            float a[4] = {a4.x, a4.y, a4.z, a4.w};
            float b[4] = {b4.x, b4.y, b4.z, b4.w};
#pragma unroll
            for (int i = 0; i < 4; ++i)
#pragma unroll
                for (int j = 0; j < 4; ++j)
                    acc[i][j] = fmaf(a[i], b[j], acc[i][j]);
        }
    }
#pragma unroll
    for (int i = 0; i < 4; ++i) {
        int m = m0 + (ty << 2) + i;
#pragma unroll
        for (int j = 0; j < 4; ++j) {
            int n = n0 + (tx << 2) + j;
            if (n < N) {
                float v = acc[i][j];
                if (EPI >= 1) v += bias[n];
                if (EPI == 2) v = softplus_f(v);
                if (EPI == 3) v += resid[(long)m * ldr + n];
                C[(long)m * ldc + n] = v;
            }
        }
    }
}

// ---------------- Depthwise causal conv (window 4) + SiLU, both directions ------------
// xi buffers are (NTOK x DI), row stride DI.
// fwd: xc[t] = silu(b + sum_k w[k]*xi[t-3+k]) ; bwd (time-flipped mamba expressed in
// unflipped coords): xc[t] = silu(b + sum_k w[k]*xi[t+3-k]).
__global__ __launch_bounds__(256) void conv_kernel(const float* __restrict__ xi_f,
                                                   const float* __restrict__ xi_b,
                                                   const float* __restrict__ wf,
                                                   const float* __restrict__ bf,
                                                   const float* __restrict__ wb,
                                                   const float* __restrict__ bb,
                                                   float* __restrict__ xc_f,
                                                   float* __restrict__ xc_b) {
    long idx = (long)blockIdx.x * 256 + threadIdx.x;
    const long per = (long)NTOK * DI;
    int dir = idx >= per;
    long i  = dir ? idx - per : idx;
    int  d  = (int)(i % DI);
    long tok = i / DI;
    int  l  = (int)(tok % SEQ);
    const float* w  = (dir ? wb : wf) + d * 4;
    float acc = (dir ? bb : bf)[d];
    const float* xi = (dir ? xi_b : xi_f) + tok * DI + d;
    if (!dir) {
#pragma unroll
        for (int k = 0; k < 4; ++k) {
            int lp = l - 3 + k;
            if (lp >= 0) acc += w[k] * xi[(long)(lp - l) * DI];
        }
    } else {
#pragma unroll
        for (int k = 0; k < 4; ++k) {
            int lp = l + 3 - k;
            if (lp < SEQ) acc += w[k] * xi[(long)(lp - l) * DI];
        }
    }
    (dir ? xc_b : xc_f)[tok * DI + d] = silu_f(acc);
}

// ---------------- Selective scan (+ skip D, + silu(z) gate), y written over xc --------
// one thread per (dir,b,d); h[16] in registers; fwd scans t ascending, bwd descending.
__global__ __launch_bounds__(256) void scan_kernel(const float* __restrict__ delta_f,
                                                   const float* __restrict__ delta_b,
                                                   float* __restrict__ xc_f,
                                                   float* __restrict__ xc_b,
                                                   const float* __restrict__ z_f,
                                                   const float* __restrict__ z_b,
                                                   const float* __restrict__ dbl_f,
                                                   const float* __restrict__ dbl_b,
                                                   const float* __restrict__ Alog_f,
                                                   const float* __restrict__ Alog_b,
                                                   const float* __restrict__ Df,
                                                   const float* __restrict__ Db) {
    int blk = blockIdx.x;            // 64 blocks: dir(2) x b(4) x dgroup(8)
    int dir = blk >> 5;
    int b   = (blk >> 3) & 3;
    int dg  = blk & 7;
    int d   = dg * 256 + threadIdx.x;
    const float* delta = dir ? delta_b : delta_f;
    float*       xc    = dir ? xc_b : xc_f;
    const float* z     = dir ? z_b : z_f;
    const float* dbl   = dir ? dbl_b : dbl_f;
    const float* Alog  = (dir ? Alog_b : Alog_f) + d * DS;
    float Dd = (dir ? Db : Df)[d];
    float Ar[DS];
#pragma unroll
    for (int s = 0; s < DS; ++s) Ar[s] = -__expf(Alog[s]);
    float h[DS];
#pragma unroll
    for (int s = 0; s < DS; ++s) h[s] = 0.f;
    for (int step = 0; step < SEQ; ++step) {
        int t = dir ? (SEQ - 1 - step) : step;
        long row = (long)b * SEQ + t;
        float dlt = delta[row * DI + d];
        float u   = xc[row * DI + d];
        float zg  = z[row * DI + d];
        const float* bc = dbl + row * 96;     // [0:64)=dt (unused), [64:80)=B, [80:96)=C
        float du = dlt * u;
        float yacc = 0.f;
#pragma unroll
        for (int s = 0; s < DS; ++s) {
            float dA = __expf(dlt * Ar[s]);
            h[s] = fmaf(h[s], dA, du * bc[64 + s]);
            yacc = fmaf(h[s], bc[80 + s], yacc);
        }
        float yo = fmaf(u, Dd, yacc);
        xc[row * DI + d] = yo * silu_f(zg);   // in-place: xc becomes gated y
    }
}

extern "C" void kernel_launch(void* const* d_in, const int* in_sizes, int n_in,
                              void* d_out, int out_size, void* d_ws, size_t ws_size,
                              hipStream_t stream) {
    const float* x      = (const float*)d_in[0];
    const float* ln_g   = (const float*)d_in[1];
    const float* ln_b   = (const float*)d_in[2];
    const float* fus_w  = (const float*)d_in[3];
    const float* fus_b  = (const float*)d_in[4];
    const float* f_in_w = (const float*)d_in[5];
    const float* f_cw   = (const float*)d_in[6];
    const float* f_cb   = (const float*)d_in[7];
    const float* f_xpw  = (const float*)d_in[8];
    const float* f_dtw  = (const float*)d_in[9];
    const float* f_dtb  = (const float*)d_in[10];
    const float* f_Alog = (const float*)d_in[11];
    const float* f_D    = (const float*)d_in[12];
    const float* f_outw = (const float*)d_in[13];
    const float* b_in_w = (const float*)d_in[14];
    const float* b_cw   = (const float*)d_in[15];
    const float* b_cb   = (const float*)d_in[16];
    const float* b_xpw  = (const float*)d_in[17];
    const float* b_dtw  = (const float*)d_in[18];
    const float* b_dtb  = (const float*)d_in[19];
    const float* b_Alog = (const float*)d_in[20];
    const float* b_D    = (const float*)d_in[21];
    const float* b_outw = (const float*)d_in[22];
    float* out = (float*)d_out;

    float* ws = (float*)d_ws;
    // workspace layout (floats), with aliasing; high-water ~52M floats = 208 MB
    const long SZ_TOKDM = (long)NTOK * DM;   // 4M
    const long SZ_TOKDI = (long)NTOK * DI;   // 8M
    float* xn      = ws;                     // [0, 4M)   dead after in-proj
    float* z_f     = xn   + SZ_TOKDM;        // [4M, 12M)
    float* z_b     = z_f  + SZ_TOKDI;        // [12M, 20M)
    float* xi_f    = z_b  + SZ_TOKDI;        // [20M, 28M)  -> delta_f -> feat
    float* xi_b    = xi_f + SZ_TOKDI;        // [28M, 36M)  -> delta_b
    float* xc_f    = xi_b + SZ_TOKDI;        // [36M, 44M)  (becomes gated y)
    float* xc_b    = xc_f + SZ_TOKDI;        // [44M, 52M)
    float* dbl_f   = xn;                     // alias xn (xn dead after step 2)
    float* dbl_b   = xn + (long)NTOK * 96;
    float* delta_f = xi_f;                   // alias xi (dead after conv)
    float* delta_b = xi_b;
    float* feat    = xi_f;                   // alias delta_f (dead after scan); 8M floats

    // 1. LayerNorm
    ln_kernel<<<NTOK, 256, 0, stream>>>(x, ln_g, ln_b, xn);
    // 2. in-proj split: xi = xn @ in_w[0:DI].T ; z = xn @ in_w[DI:2DI].T
    gemm_nt<0><<<dim3(64, 32), 256, 0, stream>>>(xn, DM, f_in_w, DM, xi_f, DI,
                                                 DI, DM, nullptr, nullptr, 0);
    gemm_nt<0><<<dim3(64, 32), 256, 0, stream>>>(xn, DM, f_in_w + (long)DI * DM, DM, z_f, DI,
                                                 DI, DM, nullptr, nullptr, 0);
    gemm_nt<0><<<dim3(64, 32), 256, 0, stream>>>(xn, DM, b_in_w, DM, xi_b, DI,
                                                 DI, DM, nullptr, nullptr, 0);
    gemm_nt<0><<<dim3(64, 32), 256, 0, stream>>>(xn, DM, b_in_w + (long)DI * DM, DM, z_b, DI,
                                                 DI, DM, nullptr, nullptr, 0);
    // 3. depthwise conv + silu (both dirs)
    conv_kernel<<<2 * NTOK * (DI / 256), 256, 0, stream>>>(xi_f, xi_b, f_cw, f_cb,
                                                           b_cw, b_cb, xc_f, xc_b);
    // 4. x-proj: dbl = xc @ xproj_w.T   (N=96, K=2048)
    gemm_nt<0><<<dim3(64, 2), 256, 0, stream>>>(xc_f, DI, f_xpw, DI, dbl_f, 96,
                                                96, DI, nullptr, nullptr, 0);
    gemm_nt<0><<<dim3(64, 2), 256, 0, stream>>>(xc_b, DI, b_xpw, DI, dbl_b, 96,
                                                96, DI, nullptr, nullptr, 0);
    // 5. dt-proj + softplus: delta = softplus(dt @ dt_w.T + dt_b)  (N=2048, K=64)
    gemm_nt<2><<<dim3(64, 32), 256, 0, stream>>>(dbl_f, 96, f_dtw, DTR, delta_f, DI,
                                                 DI, DTR, f_dtb, nullptr, 0);
    gemm_nt<2><<<dim3(64, 32), 256, 0, stream>>>(dbl_b, 96, b_dtw, DTR, delta_b, DI,
                                                 DI, DTR, b_dtb, nullptr, 0);
    // 6. selective scan + D-skip + silu(z) gate (writes gated y over xc)
    scan_kernel<<<64, 256, 0, stream>>>(delta_f, delta_b, xc_f, xc_b, z_f, z_b,
                                        dbl_f, dbl_b, f_Alog, b_Alog, f_D, b_D);
    // 7. out-proj into concat buffer feat = [y_f @ f_out_w.T | y_b @ b_out_w.T]
    //    feat: (NTOK x 2*DM), ld = 2*DM
    gemm_nt<0><<<dim3(64, 16), 256, 0, stream>>>(xc_f, DI, f_outw, DI, feat, 2 * DM,
                                                 DM, DI, nullptr, nullptr, 0);
    gemm_nt<0><<<dim3(64, 16), 256, 0, stream>>>(xc_b, DI, b_outw, DI, feat + DM, 2 * DM,
                                                 DM, DI, nullptr, nullptr, 0);
    // 8. fuse + bias + residual: out = feat @ fus_w.T + fus_b + x   (K = 2*DM)
    gemm_nt<3><<<dim3(64, 16), 256, 0, stream>>>(feat, 2 * DM, fus_w, 2 * DM, out, DM,
                                                 DM, 2 * DM, fus_b, x, DM);
}

// Round 3
// 912.535 us; speedup vs baseline: 2.9903x; 2.9903x over previous
//
#include <hip/hip_runtime.h>
#include <hip/hip_bf16.h>
#include <math.h>

#define B_SZ 4
#define SEQ  1024
#define DM   1024
#define DI   2048
#define DTR  64
#define DS   16
#define NTOK (B_SZ*SEQ)   /* 4096 tokens */

typedef __hip_bfloat16 bf16;
typedef short bf16x8 __attribute__((ext_vector_type(8)));
typedef float f32x4  __attribute__((ext_vector_type(4)));

__device__ __forceinline__ float silu_f(float x) { return x / (1.f + __expf(-x)); }
__device__ __forceinline__ float softplus_f(float x) {
    return fmaxf(x, 0.f) + log1pf(__expf(-fabsf(x)));
}
__device__ __forceinline__ void stv(float* p, float v) { *p = v; }
__device__ __forceinline__ void stv(bf16* p, float v)  { *p = __float2bfloat16(v); }
__device__ __forceinline__ unsigned short bfbits(float f) {
    union { bf16 h; unsigned short u; } c; c.h = __float2bfloat16(f); return c.u;
}

// ---------------- fp32 -> bf16 weight conversion (7 segments, one launch) ----------
struct CvtSeg { const float* s; bf16* d; int n; };
struct CvtArgs { CvtSeg seg[7]; };
__global__ __launch_bounds__(256) void cvt_kernel(CvtArgs a) {
    CvtSeg sg = a.seg[blockIdx.y];
    int base = (blockIdx.x * 256 + threadIdx.x) * 4;
    if (base >= sg.n) return;
    float4 v = *(const float4*)(sg.s + base);
    ushort4 o;
    o.x = bfbits(v.x); o.y = bfbits(v.y); o.z = bfbits(v.z); o.w = bfbits(v.w);
    *(ushort4*)(sg.d + base) = o;
}

// ---------------- LayerNorm over last dim (1024), bf16 out ----------------
__global__ __launch_bounds__(256) void ln_kernel(const float* __restrict__ x,
                                                 const float* __restrict__ g,
                                                 const float* __restrict__ be,
                                                 bf16* __restrict__ xn) {
    int row = blockIdx.x;
    const float* xr = x + (long)row * DM;
    float v[4];
    float s = 0.f, ss = 0.f;
#pragma unroll
    for (int i = 0; i < 4; ++i) {
        v[i] = xr[threadIdx.x + 256 * i];
        s += v[i]; ss += v[i] * v[i];
    }
#pragma unroll
    for (int off = 32; off >= 1; off >>= 1) {
        s  += __shfl_xor(s, off, 64);
        ss += __shfl_xor(ss, off, 64);
    }
    __shared__ float sh[8];
    int wid = threadIdx.x >> 6;
    if ((threadIdx.x & 63) == 0) { sh[wid] = s; sh[4 + wid] = ss; }
    __syncthreads();
    s  = sh[0] + sh[1] + sh[2] + sh[3];
    ss = sh[4] + sh[5] + sh[6] + sh[7];
    float mu  = s / DM;
    float var = ss / DM - mu * mu;
    float rs  = rsqrtf(var + 1e-5f);
    bf16* xo = xn + (long)row * DM;
#pragma unroll
    for (int i = 0; i < 4; ++i) {
        int c = threadIdx.x + 256 * i;
        xo[c] = __float2bfloat16((v[i] - mu) * rs * g[c] + be[c]);
    }
}

// ---------------- bf16 MFMA GEMM: C[m,n] = sum_k A[m,k]*B[n,k] ----------------
// 128x128 block tile, BK=32, 256 thr = 4 waves (2x2 of 64x64), 16x16x32 MFMA.
// LDS XOR-swizzle: slot (r,q) holds global k-chunk q^(r&3) -> frag ds_read_b128
// lands 2-way bank aliasing (free). B rows clamped to N-1 (garbage cols masked).
struct GPtr { const bf16* A; const bf16* B; void* C; };
struct GB4 { GPtr p[4]; };

template <int EPI, typename OutT>   // EPI: 0 none, 1 +bias, 3 +bias+resid
__global__ __launch_bounds__(256) void gemm_mfma(GB4 gb, int lda, int ldb, int ldc,
                                                 int N, int K,
                                                 const float* __restrict__ bias,
                                                 const float* __restrict__ resid, int ldr) {
    __shared__ __align__(16) short As[128 * 32];
    __shared__ __align__(16) short Bs[128 * 32];
    GPtr g = gb.p[blockIdx.z];
    const short* A = (const short*)g.A;
    const short* B = (const short*)g.B;
    OutT* C = (OutT*)g.C;
    const int tid = threadIdx.x;
    const int m0 = blockIdx.x * 128, n0 = blockIdx.y * 128;
    const int lane = tid & 63, wv = tid >> 6;
    const int wm = (wv >> 1) * 64, wn = (wv & 1) * 64;
    const int r0 = tid >> 2;          // 0..63 staged row
    const int q0 = tid & 3;           // 16B chunk slot within row
    f32x4 acc[4][4];
#pragma unroll
    for (int i = 0; i < 4; ++i)
#pragma unroll
        for (int j = 0; j < 4; ++j) acc[i][j] = (f32x4){0.f, 0.f, 0.f, 0.f};

    for (int k0 = 0; k0 < K; k0 += 32) {
        __syncthreads();
#pragma unroll
        for (int p = 0; p < 2; ++p) {
            int r  = p * 64 + r0;
            int qa = q0 ^ (r & 3);                 // swizzled source chunk
            *(bf16x8*)&As[r * 32 + q0 * 8] =
                *(const bf16x8*)(A + (long)(m0 + r) * lda + k0 + qa * 8);
            int rb = n0 + r; rb = rb < N ? rb : N - 1;
            *(bf16x8*)&Bs[r * 32 + q0 * 8] =
                *(const bf16x8*)(B + (long)rb * ldb + k0 + qa * 8);
        }
        __syncthreads();
        bf16x8 af[4], bfr[4];
#pragma unroll
        for (int t = 0; t < 4; ++t) {
            int ra = wm + t * 16 + (lane & 15);
            af[t]  = *(const bf16x8*)&As[ra * 32 + (((lane >> 4) ^ (ra & 3)) * 8)];
            int rb = wn + t * 16 + (lane & 15);
            bfr[t] = *(const bf16x8*)&Bs[rb * 32 + (((lane >> 4) ^ (rb & 3)) * 8)];
        }
#pragma unroll
        for (int i = 0; i < 4; ++i)
#pragma unroll
            for (int j = 0; j < 4; ++j)
                acc[i][j] = __builtin_amdgcn_mfma_f32_16x16x32_bf16(af[i], bfr[j], acc[i][j], 0, 0, 0);
    }
    // epilogue: C/D layout col=lane&15, row=(lane>>4)*4+reg
#pragma unroll
    for (int i = 0; i < 4; ++i) {
        int rowb = m0 + wm + i * 16 + ((lane >> 4) << 2);
#pragma unroll
        for (int j = 0; j < 4; ++j) {
            int col = n0 + wn + j * 16 + (lane & 15);
            if (col < N) {
#pragma unroll
                for (int rr = 0; rr < 4; ++rr) {
                    float v = acc[i][j][rr];
                    if (EPI >= 1) v += bias[col];
                    if (EPI == 3) v += resid[(long)(rowb + rr) * ldr + col];
                    stv(&C[(long)(rowb + rr) * ldc + col], v);
                }
            }
        }
    }
}

// ---------------- fp32 vector GEMM (dt-proj only): C = A @ B.T ----------------
template <int EPI, typename OutT>   // EPI: 2 = softplus(acc+bias)
__global__ __launch_bounds__(256) void gemm_nt(const float* __restrict__ A, int lda,
                                               const float* __restrict__ B, int ldb,
                                               OutT* __restrict__ C, int ldc,
                                               int N, int K,
                                               const float* __restrict__ bias) {
    __shared__ __align__(16) float As[16][68];
    __shared__ __align__(16) float Bs[16][68];
    const int tid = threadIdx.x;
    const int m0  = blockIdx.x * 64;
    const int n0  = blockIdx.y * 64;
    const int lr  = tid >> 2;
    const int lc  = (tid & 3) << 2;
    const int ty  = tid >> 4;
    const int tx  = tid & 15;
    float acc[4][4] = {};
    const float* ap0 = A + (long)(m0 + lr) * lda + lc;
    const float* bp0 = B + (long)(n0 + lr) * ldb + lc;
    for (int k0 = 0; k0 < K; k0 += 16) {
        float4 av = *(const float4*)(ap0 + k0);
        float4 bv = *(const float4*)(bp0 + k0);
        __syncthreads();
        As[lc + 0][lr] = av.x; As[lc + 1][lr] = av.y; As[lc + 2][lr] = av.z; As[lc + 3][lr] = av.w;
        Bs[lc + 0][lr] = bv.x; Bs[lc + 1][lr] = bv.y; Bs[lc + 2][lr] = bv.z; Bs[lc + 3][lr] = bv.w;
        __syncthreads();
#pragma unroll
        for (int kk = 0; kk < 16; ++kk) {
            float4 a4 = *(const float4*)&As[kk][ty << 2];
            float4 b4 = *(const float4*)&Bs[kk][tx << 2];
            float a[4] = {a4.x, a4.y, a4.z, a4.w};
            float b[4] = {b4.x, b4.y, b4.z, b4.w};
#pragma unroll
            for (int i = 0; i < 4; ++i)
#pragma unroll
                for (int j = 0; j < 4; ++j)
                    acc[i][j] = fmaf(a[i], b[j], acc[i][j]);
        }
    }
#pragma unroll
    for (int i = 0; i < 4; ++i) {
        int m = m0 + (ty << 2) + i;
#pragma unroll
        for (int j = 0; j < 4; ++j) {
            int n = n0 + (tx << 2) + j;
            float v = acc[i][j];
            if (EPI >= 1) v += bias[n];
            if (EPI == 2) v = softplus_f(v);
            stv(&C[(long)m * ldc + n], v);
        }
    }
}

// ---------------- Depthwise causal conv (window 4) + SiLU, bf16 ------------
__global__ __launch_bounds__(256) void conv_kernel(const bf16* __restrict__ xi_f,
                                                   const bf16* __restrict__ xi_b,
                                                   const float* __restrict__ wf,
                                                   const float* __restrict__ bfs,
                                                   const float* __restrict__ wb,
                                                   const float* __restrict__ bb,
                                                   bf16* __restrict__ xc_f,
                                                   bf16* __restrict__ xc_b) {
    long idx = (long)blockIdx.x * 256 + threadIdx.x;
    const long per = (long)NTOK * DI;
    int dir = idx >= per;
    long i  = dir ? idx - per : idx;
    int  d  = (int)(i % DI);
    long tok = i / DI;
    int  l  = (int)(tok % SEQ);
    const float* w  = (dir ? wb : wf) + d * 4;
    float acc = (dir ? bb : bfs)[d];
    const bf16* xi = (dir ? xi_b : xi_f) + tok * DI + d;
    if (!dir) {
#pragma unroll
        for (int k = 0; k < 4; ++k) {
            int lp = l - 3 + k;
            if (lp >= 0) acc += w[k] * __bfloat162float(xi[(long)(lp - l) * DI]);
        }
    } else {
#pragma unroll
        for (int k = 0; k < 4; ++k) {
            int lp = l + 3 - k;
            if (lp < SEQ) acc += w[k] * __bfloat162float(xi[(long)(lp - l) * DI]);
        }
    }
    (dir ? xc_b : xc_f)[tok * DI + d] = __float2bfloat16(silu_f(acc));
}

// ---------------- Selective scan, 4-way state split + prefetch ----------------
// lane = sub*16 + di: 4 lane-groups each own 4 of the 16 states of channel d.
// y reduced via shfl_xor(16/32); gated output written in-place over xc (u).
__global__ __launch_bounds__(256) void scan_kernel(
        const bf16* __restrict__ delta_f, const bf16* __restrict__ delta_b,
        bf16* __restrict__ xc_f, bf16* __restrict__ xc_b,
        const bf16* __restrict__ z_f, const bf16* __restrict__ z_b,
        const float* __restrict__ dbl_f, const float* __restrict__ dbl_b,
        const float* __restrict__ Alog_f, const float* __restrict__ Alog_b,
        const float* __restrict__ Df, const float* __restrict__ Db) {
    int blk = blockIdx.x;            // 256 blocks: dir(2) x b(4) x dgrp(32)
    int dir = blk >> 7;
    int b   = (blk >> 5) & 3;
    int dg  = blk & 31;
    int lane = threadIdx.x & 63, wv = threadIdx.x >> 6;
    int di  = lane & 15, sub = lane >> 4;
    int d   = dg * 64 + wv * 16 + di;
    const bf16* delta = dir ? delta_b : delta_f;
    bf16*       xc    = dir ? xc_b : xc_f;
    const bf16* z     = dir ? z_b : z_f;
    const float* dbl  = dir ? dbl_b : dbl_f;
    const float* Alog = (dir ? Alog_b : Alog_f) + d * DS + sub * 4;
    float Dd = (dir ? Db : Df)[d];
    float Ar[4], h[4] = {0.f, 0.f, 0.f, 0.f};
#pragma unroll
    for (int j = 0; j < 4; ++j) Ar[j] = -__expf(Alog[j]);
    long row = (long)b * SEQ + (dir ? SEQ - 1 : 0);
    long tstep = dir ? -1 : 1;
    float dlt = __bfloat162float(delta[row * DI + d]);
    float u   = __bfloat162float(xc[row * DI + d]);
    float zg  = __bfloat162float(z[row * DI + d]);
    float Bv[4], Cv[4];
#pragma unroll
    for (int j = 0; j < 4; ++j) {
        Bv[j] = dbl[row * 96 + 64 + sub * 4 + j];
        Cv[j] = dbl[row * 96 + 80 + sub * 4 + j];
    }
    for (int step = 0; step < SEQ; ++step) {
        long rown = row + tstep;
        float dltn = 0.f, un = 0.f, zgn = 0.f;
        float Bn[4] = {0.f,0.f,0.f,0.f}, Cn[4] = {0.f,0.f,0.f,0.f};
        if (step + 1 < SEQ) {                        // prefetch next step
            dltn = __bfloat162float(delta[rown * DI + d]);
            un   = __bfloat162float(xc[rown * DI + d]);
            zgn  = __bfloat162float(z[rown * DI + d]);
#pragma unroll
            for (int j = 0; j < 4; ++j) {
                Bn[j] = dbl[rown * 96 + 64 + sub * 4 + j];
                Cn[j] = dbl[rown * 96 + 80 + sub * 4 + j];
            }
        }
        float du = dlt * u;
        float y = 0.f;
#pragma unroll
        for (int j = 0; j < 4; ++j) {
            float dA = __expf(dlt * Ar[j]);
            h[j] = fmaf(h[j], dA, du * Bv[j]);
            y = fmaf(h[j], Cv[j], y);
        }
        y += __shfl_xor(y, 16, 64);
        y += __shfl_xor(y, 32, 64);
        if (sub == 0) {
            float yo = fmaf(u, Dd, y);
            xc[row * DI + d] = __float2bfloat16(yo * silu_f(zg));
        }
        row = rown; dlt = dltn; u = un; zg = zgn;
#pragma unroll
        for (int j = 0; j < 4; ++j) { Bv[j] = Bn[j]; Cv[j] = Cn[j]; }
    }
}

extern "C" void kernel_launch(void* const* d_in, const int* in_sizes, int n_in,
                              void* d_out, int out_size, void* d_ws, size_t ws_size,
                              hipStream_t stream) {
    const float* x      = (const float*)d_in[0];
    const float* ln_g   = (const float*)d_in[1];
    const float* ln_b   = (const float*)d_in[2];
    const float* fus_w  = (const float*)d_in[3];
    const float* fus_b  = (const float*)d_in[4];
    const float* f_in_w = (const float*)d_in[5];
    const float* f_cw   = (const float*)d_in[6];
    const float* f_cb   = (const float*)d_in[7];
    const float* f_xpw  = (const float*)d_in[8];
    const float* f_dtw  = (const float*)d_in[9];
    const float* f_dtb  = (const float*)d_in[10];
    const float* f_Alog = (const float*)d_in[11];
    const float* f_D    = (const float*)d_in[12];
    const float* f_outw = (const float*)d_in[13];
    const float* b_in_w = (const float*)d_in[14];
    const float* b_cw   = (const float*)d_in[15];
    const float* b_cb   = (const float*)d_in[16];
    const float* b_xpw  = (const float*)d_in[17];
    const float* b_dtw  = (const float*)d_in[18];
    const float* b_dtb  = (const float*)d_in[19];
    const float* b_Alog = (const float*)d_in[20];
    const float* b_D    = (const float*)d_in[21];
    const float* b_outw = (const float*)d_in[22];
    float* out = (float*)d_out;

    char* w = (char*)d_ws;
    auto alloc = [&](size_t bytes) { char* p = w; w += (bytes + 255) & ~255UL; return p; };
    bf16* xn   = (bf16*)alloc((size_t)NTOK * DM * 2);      // 8 MB
    bf16* xi_f = (bf16*)alloc((size_t)NTOK * DI * 2);      // 16 MB (-> delta_f)
    bf16* xi_b = (bf16*)alloc((size_t)NTOK * DI * 2);      // 16 MB (-> delta_b)
    bf16* z_f  = (bf16*)alloc((size_t)NTOK * DI * 2);
    bf16* z_b  = (bf16*)alloc((size_t)NTOK * DI * 2);
    bf16* xc_f = (bf16*)alloc((size_t)NTOK * DI * 2);      // u, then gated y
    bf16* xc_b = (bf16*)alloc((size_t)NTOK * DI * 2);
    bf16* feat = (bf16*)alloc((size_t)NTOK * 2 * DM * 2);  // 16 MB
    float* dbl_f = (float*)alloc((size_t)NTOK * 96 * 4);
    float* dbl_b = (float*)alloc((size_t)NTOK * 96 * 4);
    bf16* w_fin  = (bf16*)alloc((size_t)2 * DI * DM * 2);  // 8 MB
    bf16* w_bin  = (bf16*)alloc((size_t)2 * DI * DM * 2);
    bf16* w_fout = (bf16*)alloc((size_t)DM * DI * 2);
    bf16* w_bout = (bf16*)alloc((size_t)DM * DI * 2);
    bf16* w_fus  = (bf16*)alloc((size_t)DM * 2 * DM * 2);
    bf16* w_fxp  = (bf16*)alloc((size_t)96 * DI * 2);
    bf16* w_bxp  = (bf16*)alloc((size_t)96 * DI * 2);
    bf16* delta_f = xi_f;      // alias: xi dead after conv
    bf16* delta_b = xi_b;

    // 0. weight conversion
    CvtArgs ca;
    ca.seg[0] = {f_in_w, w_fin,  2 * DI * DM};
    ca.seg[1] = {b_in_w, w_bin,  2 * DI * DM};
    ca.seg[2] = {f_outw, w_fout, DM * DI};
    ca.seg[3] = {b_outw, w_bout, DM * DI};
    ca.seg[4] = {fus_w,  w_fus,  DM * 2 * DM};
    ca.seg[5] = {f_xpw,  w_fxp,  96 * DI};
    ca.seg[6] = {b_xpw,  w_bxp,  96 * DI};
    cvt_kernel<<<dim3(4096, 7), 256, 0, stream>>>(ca);
    // 1. LayerNorm -> bf16
    ln_kernel<<<NTOK, 256, 0, stream>>>(x, ln_g, ln_b, xn);
    // 2. in-proj (batched z=4): xi/z for both dirs
    {
        GB4 gb{};
        gb.p[0] = {xn, w_fin,                      xi_f};
        gb.p[1] = {xn, w_fin + (size_t)DI * DM,    z_f};
        gb.p[2] = {xn, w_bin,                      xi_b};
        gb.p[3] = {xn, w_bin + (size_t)DI * DM,    z_b};
        gemm_mfma<0, bf16><<<dim3(32, 16, 4), 256, 0, stream>>>(gb, DM, DM, DI, DI, DM,
                                                                nullptr, nullptr, 0);
    }
    // 3. depthwise conv + silu
    conv_kernel<<<2 * NTOK * (DI / 256), 256, 0, stream>>>(xi_f, xi_b, f_cw, f_cb,
                                                           b_cw, b_cb, xc_f, xc_b);
    // 4. x-proj (batched z=2): dbl = xc @ xproj.T (N=96, fp32 out)
    {
        GB4 gb{};
        gb.p[0] = {xc_f, w_fxp, dbl_f};
        gb.p[1] = {xc_b, w_bxp, dbl_b};
        gemm_mfma<0, float><<<dim3(32, 1, 2), 256, 0, stream>>>(gb, DI, DI, 96, 96, DI,
                                                                nullptr, nullptr, 0);
    }
    // 5. dt-proj + softplus -> bf16 delta (fp32 vector GEMM, K=64)
    gemm_nt<2, bf16><<<dim3(64, 32), 256, 0, stream>>>(dbl_f, 96, f_dtw, DTR,
                                                       delta_f, DI, DI, DTR, f_dtb);
    gemm_nt<2, bf16><<<dim3(64, 32), 256, 0, stream>>>(dbl_b, 96, b_dtw, DTR,
                                                       delta_b, DI, DI, DTR, b_dtb);
    // 6. selective scan + D-skip + silu(z) gate (in-place over xc)
    scan_kernel<<<256, 256, 0, stream>>>(delta_f, delta_b, xc_f, xc_b, z_f, z_b,
                                         dbl_f, dbl_b, f_Alog, b_Alog, f_D, b_D);
    // 7. out-proj (batched z=2) -> feat bf16 [y_f@W | y_b@W]
    {
        GB4 gb{};
        gb.p[0] = {xc_f, w_fout, feat};
        gb.p[1] = {xc_b, w_bout, feat + DM};
        gemm_mfma<0, bf16><<<dim3(32, 8, 2), 256, 0, stream>>>(gb, DI, DI, 2 * DM, DM, DI,
                                                               nullptr, nullptr, 0);
    }
    // 8. fuse + bias + residual (fp32 out)
    {
        GB4 gb{};
        gb.p[0] = {feat, w_fus, out};
        gemm_mfma<3, float><<<dim3(32, 8, 1), 256, 0, stream>>>(gb, 2 * DM, 2 * DM, DM,
                                                                DM, 2 * DM, fus_b, x, DM);
    }
}

// Round 4
// 755.534 us; speedup vs baseline: 3.6117x; 1.2078x over previous
//
#include <hip/hip_runtime.h>
#include <hip/hip_bf16.h>
#include <math.h>

#define B_SZ 4
#define SEQ  1024
#define DM   1024
#define DI   2048
#define DTR  64
#define DS   16
#define NTOK (B_SZ*SEQ)   /* 4096 tokens */
#define CHUNKS 16
#define CLEN   64         /* SEQ / CHUNKS */

typedef __hip_bfloat16 bf16;
typedef short bf16x8 __attribute__((ext_vector_type(8)));
typedef float f32x4  __attribute__((ext_vector_type(4)));

__device__ __forceinline__ float silu_f(float x) { return x / (1.f + __expf(-x)); }
__device__ __forceinline__ float softplus_f(float x) {
    return fmaxf(x, 0.f) + log1pf(__expf(-fabsf(x)));
}
__device__ __forceinline__ void stv(float* p, float v) { *p = v; }
__device__ __forceinline__ void stv(bf16* p, float v)  { *p = __float2bfloat16(v); }
__device__ __forceinline__ unsigned short bfbits(float f) {
    union { bf16 h; unsigned short u; } c; c.h = __float2bfloat16(f); return c.u;
}

// ---------------- fp32 -> bf16 weight conversion (7 segments, one launch) ----------
struct CvtSeg { const float* s; bf16* d; int n; };
struct CvtArgs { CvtSeg seg[7]; };
__global__ __launch_bounds__(256) void cvt_kernel(CvtArgs a) {
    CvtSeg sg = a.seg[blockIdx.y];
    int base = (blockIdx.x * 256 + threadIdx.x) * 4;
    if (base >= sg.n) return;
    float4 v = *(const float4*)(sg.s + base);
    ushort4 o;
    o.x = bfbits(v.x); o.y = bfbits(v.y); o.z = bfbits(v.z); o.w = bfbits(v.w);
    *(ushort4*)(sg.d + base) = o;
}

// ---------------- LayerNorm over last dim (1024), bf16 out ----------------
__global__ __launch_bounds__(256) void ln_kernel(const float* __restrict__ x,
                                                 const float* __restrict__ g,
                                                 const float* __restrict__ be,
                                                 bf16* __restrict__ xn) {
    int row = blockIdx.x;
    const float* xr = x + (long)row * DM;
    float v[4];
    float s = 0.f, ss = 0.f;
#pragma unroll
    for (int i = 0; i < 4; ++i) {
        v[i] = xr[threadIdx.x + 256 * i];
        s += v[i]; ss += v[i] * v[i];
    }
#pragma unroll
    for (int off = 32; off >= 1; off >>= 1) {
        s  += __shfl_xor(s, off, 64);
        ss += __shfl_xor(ss, off, 64);
    }
    __shared__ float sh[8];
    int wid = threadIdx.x >> 6;
    if ((threadIdx.x & 63) == 0) { sh[wid] = s; sh[4 + wid] = ss; }
    __syncthreads();
    s  = sh[0] + sh[1] + sh[2] + sh[3];
    ss = sh[4] + sh[5] + sh[6] + sh[7];
    float mu  = s / DM;
    float var = ss / DM - mu * mu;
    float rs  = rsqrtf(var + 1e-5f);
    bf16* xo = xn + (long)row * DM;
#pragma unroll
    for (int i = 0; i < 4; ++i) {
        int c = threadIdx.x + 256 * i;
        xo[c] = __float2bfloat16((v[i] - mu) * rs * g[c] + be[c]);
    }
}

// ---------------- bf16 MFMA GEMM: C[m,n] = sum_k A[m,k]*B[n,k] ----------------
struct GPtr { const bf16* A; const bf16* B; void* C; };
struct GB4 { GPtr p[4]; };

template <int EPI, typename OutT>   // EPI: 0 none, 1 +bias, 3 +bias+resid
__global__ __launch_bounds__(256) void gemm_mfma(GB4 gb, int lda, int ldb, int ldc,
                                                 int N, int K,
                                                 const float* __restrict__ bias,
                                                 const float* __restrict__ resid, int ldr) {
    __shared__ __align__(16) short As[128 * 32];
    __shared__ __align__(16) short Bs[128 * 32];
    GPtr g = gb.p[blockIdx.z];
    const short* A = (const short*)g.A;
    const short* B = (const short*)g.B;
    OutT* C = (OutT*)g.C;
    const int tid = threadIdx.x;
    const int m0 = blockIdx.x * 128, n0 = blockIdx.y * 128;
    const int lane = tid & 63, wv = tid >> 6;
    const int wm = (wv >> 1) * 64, wn = (wv & 1) * 64;
    const int r0 = tid >> 2;
    const int q0 = tid & 3;
    f32x4 acc[4][4];
#pragma unroll
    for (int i = 0; i < 4; ++i)
#pragma unroll
        for (int j = 0; j < 4; ++j) acc[i][j] = (f32x4){0.f, 0.f, 0.f, 0.f};

    for (int k0 = 0; k0 < K; k0 += 32) {
        __syncthreads();
#pragma unroll
        for (int p = 0; p < 2; ++p) {
            int r  = p * 64 + r0;
            int qa = q0 ^ (r & 3);
            *(bf16x8*)&As[r * 32 + q0 * 8] =
                *(const bf16x8*)(A + (long)(m0 + r) * lda + k0 + qa * 8);
            int rb = n0 + r; rb = rb < N ? rb : N - 1;
            *(bf16x8*)&Bs[r * 32 + q0 * 8] =
                *(const bf16x8*)(B + (long)rb * ldb + k0 + qa * 8);
        }
        __syncthreads();
        bf16x8 af[4], bfr[4];
#pragma unroll
        for (int t = 0; t < 4; ++t) {
            int ra = wm + t * 16 + (lane & 15);
            af[t]  = *(const bf16x8*)&As[ra * 32 + (((lane >> 4) ^ (ra & 3)) * 8)];
            int rb = wn + t * 16 + (lane & 15);
            bfr[t] = *(const bf16x8*)&Bs[rb * 32 + (((lane >> 4) ^ (rb & 3)) * 8)];
        }
#pragma unroll
        for (int i = 0; i < 4; ++i)
#pragma unroll
            for (int j = 0; j < 4; ++j)
                acc[i][j] = __builtin_amdgcn_mfma_f32_16x16x32_bf16(af[i], bfr[j], acc[i][j], 0, 0, 0);
    }
#pragma unroll
    for (int i = 0; i < 4; ++i) {
        int rowb = m0 + wm + i * 16 + ((lane >> 4) << 2);
#pragma unroll
        for (int j = 0; j < 4; ++j) {
            int col = n0 + wn + j * 16 + (lane & 15);
            if (col < N) {
#pragma unroll
                for (int rr = 0; rr < 4; ++rr) {
                    float v = acc[i][j][rr];
                    if (EPI >= 1) v += bias[col];
                    if (EPI == 3) v += resid[(long)(rowb + rr) * ldr + col];
                    stv(&C[(long)(rowb + rr) * ldc + col], v);
                }
            }
        }
    }
}

// ---------------- fp32 vector GEMM (dt-proj only): C = A @ B.T ----------------
template <int EPI, typename OutT>   // EPI: 2 = softplus(acc+bias)
__global__ __launch_bounds__(256) void gemm_nt(const float* __restrict__ A, int lda,
                                               const float* __restrict__ B, int ldb,
                                               OutT* __restrict__ C, int ldc,
                                               int N, int K,
                                               const float* __restrict__ bias) {
    __shared__ __align__(16) float As[16][68];
    __shared__ __align__(16) float Bs[16][68];
    const int tid = threadIdx.x;
    const int m0  = blockIdx.x * 64;
    const int n0  = blockIdx.y * 64;
    const int lr  = tid >> 2;
    const int lc  = (tid & 3) << 2;
    const int ty  = tid >> 4;
    const int tx  = tid & 15;
    float acc[4][4] = {};
    const float* ap0 = A + (long)(m0 + lr) * lda + lc;
    const float* bp0 = B + (long)(n0 + lr) * ldb + lc;
    for (int k0 = 0; k0 < K; k0 += 16) {
        float4 av = *(const float4*)(ap0 + k0);
        float4 bv = *(const float4*)(bp0 + k0);
        __syncthreads();
        As[lc + 0][lr] = av.x; As[lc + 1][lr] = av.y; As[lc + 2][lr] = av.z; As[lc + 3][lr] = av.w;
        Bs[lc + 0][lr] = bv.x; Bs[lc + 1][lr] = bv.y; Bs[lc + 2][lr] = bv.z; Bs[lc + 3][lr] = bv.w;
        __syncthreads();
#pragma unroll
        for (int kk = 0; kk < 16; ++kk) {
            float4 a4 = *(const float4*)&As[kk][ty << 2];
            float4 b4 = *(const float4*)&Bs[kk][tx << 2];
            float a[4] = {a4.x, a4.y, a4.z, a4.w};
            float b[4] = {b4.x, b4.y, b4.z, b4.w};
#pragma unroll
            for (int i = 0; i < 4; ++i)
#pragma unroll
                for (int j = 0; j < 4; ++j)
                    acc[i][j] = fmaf(a[i], b[j], acc[i][j]);
        }
    }
#pragma unroll
    for (int i = 0; i < 4; ++i) {
        int m = m0 + (ty << 2) + i;
#pragma unroll
        for (int j = 0; j < 4; ++j) {
            int n = n0 + (tx << 2) + j;
            float v = acc[i][j];
            if (EPI >= 1) v += bias[n];
            if (EPI == 2) v = softplus_f(v);
            stv(&C[(long)m * ldc + n], v);
        }
    }
}

// ---------------- Depthwise causal conv (window 4) + SiLU, bf16 ------------
__global__ __launch_bounds__(256) void conv_kernel(const bf16* __restrict__ xi_f,
                                                   const bf16* __restrict__ xi_b,
                                                   const float* __restrict__ wf,
                                                   const float* __restrict__ bfs,
                                                   const float* __restrict__ wb,
                                                   const float* __restrict__ bb,
                                                   bf16* __restrict__ xc_f,
                                                   bf16* __restrict__ xc_b) {
    long idx = (long)blockIdx.x * 256 + threadIdx.x;
    const long per = (long)NTOK * DI;
    int dir = idx >= per;
    long i  = dir ? idx - per : idx;
    int  d  = (int)(i % DI);
    long tok = i / DI;
    int  l  = (int)(tok % SEQ);
    const float* w  = (dir ? wb : wf) + d * 4;
    float acc = (dir ? bb : bfs)[d];
    const bf16* xi = (dir ? xi_b : xi_f) + tok * DI + d;
    if (!dir) {
#pragma unroll
        for (int k = 0; k < 4; ++k) {
            int lp = l - 3 + k;
            if (lp >= 0) acc += w[k] * __bfloat162float(xi[(long)(lp - l) * DI]);
        }
    } else {
#pragma unroll
        for (int k = 0; k < 4; ++k) {
            int lp = l + 3 - k;
            if (lp < SEQ) acc += w[k] * __bfloat162float(xi[(long)(lp - l) * DI]);
        }
    }
    (dir ? xc_b : xc_f)[tok * DI + d] = __float2bfloat16(silu_f(acc));
}

// =========== Chunked selective scan: h_t = dA*h + (delta*u)*B, y = <h,C> ===========
// Thread layout (all passes): lane = sub*16 + di (4 subs x 4 states each), wave wv
// owns channels d = dg*64 + wv*16 + di. Chunk c covers scan steps tau in [c*64,(c+1)*64),
// t = dir ? SEQ-1-tau : tau.
// red_a / red_b: per (dir,b,chunk): DI*16 floats at offset (((dir*4+b)*CHUNKS+c)*DI*16),
// element d*16 + s. Pass1 writes aprod->red_a, bacc->red_b. Pass2 reads both, rewrites
// red_a with h_init per chunk. Pass3 reads h_init, emits gated y in-place over xc.

__global__ __launch_bounds__(256) void scan_reduce(
        const bf16* __restrict__ delta_f, const bf16* __restrict__ delta_b,
        const bf16* __restrict__ xc_f, const bf16* __restrict__ xc_b,
        const float* __restrict__ dbl_f, const float* __restrict__ dbl_b,
        const float* __restrict__ Alog_f, const float* __restrict__ Alog_b,
        float* __restrict__ red_a, float* __restrict__ red_b) {
    int blk = blockIdx.x;            // dir(2) x b(4) x c(16) x dgrp(32) = 4096
    int dg  = blk & 31;
    int c   = (blk >> 5) & 15;
    int b   = (blk >> 9) & 3;
    int dir = blk >> 11;
    int lane = threadIdx.x & 63, wv = threadIdx.x >> 6;
    int di = lane & 15, sub = lane >> 4;
    int d  = dg * 64 + wv * 16 + di;
    const bf16* delta = dir ? delta_b : delta_f;
    const bf16* xc    = dir ? xc_b : xc_f;
    const float* dbl  = dir ? dbl_b : dbl_f;
    const float* Alog = (dir ? Alog_b : Alog_f) + d * DS + sub * 4;
    float Ar[4], aprod[4] = {1.f,1.f,1.f,1.f}, bacc[4] = {0.f,0.f,0.f,0.f};
#pragma unroll
    for (int j = 0; j < 4; ++j) Ar[j] = -__expf(Alog[j]);
    long tstep = dir ? -1 : 1;
    long row = (long)b * SEQ + (dir ? SEQ - 1 - c * CLEN : c * CLEN);
    float dlt = __bfloat162float(delta[row * DI + d]);
    float u   = __bfloat162float(xc[row * DI + d]);
    f32x4 Bv  = *(const f32x4*)(dbl + row * 96 + 64 + sub * 4);
    for (int s = 0; s < CLEN; ++s) {
        long rown = row + tstep;
        float dltn = 0.f, un = 0.f; f32x4 Bn = (f32x4){0.f,0.f,0.f,0.f};
        if (s + 1 < CLEN) {
            dltn = __bfloat162float(delta[rown * DI + d]);
            un   = __bfloat162float(xc[rown * DI + d]);
            Bn   = *(const f32x4*)(dbl + rown * 96 + 64 + sub * 4);
        }
        float du = dlt * u;
#pragma unroll
        for (int j = 0; j < 4; ++j) {
            float dA = __expf(dlt * Ar[j]);
            bacc[j]  = fmaf(bacc[j], dA, du * Bv[j]);
            aprod[j] *= dA;
        }
        row = rown; dlt = dltn; u = un; Bv = Bn;
    }
    long base = (((long)(dir * 4 + b) * CHUNKS + c) * DI + d) * 16 + sub * 4;
    *(f32x4*)(red_a + base) = (f32x4){aprod[0], aprod[1], aprod[2], aprod[3]};
    *(f32x4*)(red_b + base) = (f32x4){bacc[0], bacc[1], bacc[2], bacc[3]};
}

__global__ __launch_bounds__(256) void scan_combine(float* __restrict__ red_a,
                                                    const float* __restrict__ red_b) {
    int tid = blockIdx.x * 256 + threadIdx.x;   // 65536 threads: (dir,b,d,sub)
    int sub = tid & 3;
    int d   = (tid >> 2) & 2047;
    int db  = tid >> 13;                        // dir*4+b
    f32x4 h = (f32x4){0.f, 0.f, 0.f, 0.f};
    for (int c = 0; c < CHUNKS; ++c) {
        long idx = (((long)db * CHUNKS + c) * DI + d) * 16 + sub * 4;
        f32x4 a = *(const f32x4*)(red_a + idx);
        f32x4 w = *(const f32x4*)(red_b + idx);
        *(f32x4*)(red_a + idx) = h;             // h_init for chunk c
#pragma unroll
        for (int j = 0; j < 4; ++j) h[j] = fmaf(a[j], h[j], w[j]);
    }
}

__global__ __launch_bounds__(256) void scan_apply(
        const bf16* __restrict__ delta_f, const bf16* __restrict__ delta_b,
        bf16* __restrict__ xc_f, bf16* __restrict__ xc_b,
        const bf16* __restrict__ z_f, const bf16* __restrict__ z_b,
        const float* __restrict__ dbl_f, const float* __restrict__ dbl_b,
        const float* __restrict__ Alog_f, const float* __restrict__ Alog_b,
        const float* __restrict__ Df, const float* __restrict__ Db,
        const float* __restrict__ red_a) {
    int blk = blockIdx.x;            // dir(2) x b(4) x c(16) x dgrp(32)
    int dg  = blk & 31;
    int c   = (blk >> 5) & 15;
    int b   = (blk >> 9) & 3;
    int dir = blk >> 11;
    int lane = threadIdx.x & 63, wv = threadIdx.x >> 6;
    int di = lane & 15, sub = lane >> 4;
    int d  = dg * 64 + wv * 16 + di;
    const bf16* delta = dir ? delta_b : delta_f;
    bf16*       xc    = dir ? xc_b : xc_f;
    const bf16* z     = dir ? z_b : z_f;
    const float* dbl  = dir ? dbl_b : dbl_f;
    const float* Alog = (dir ? Alog_b : Alog_f) + d * DS + sub * 4;
    float Dd = (dir ? Db : Df)[d];
    float Ar[4], h[4];
#pragma unroll
    for (int j = 0; j < 4; ++j) Ar[j] = -__expf(Alog[j]);
    {
        long base = (((long)(dir * 4 + b) * CHUNKS + c) * DI + d) * 16 + sub * 4;
        f32x4 h0 = *(const f32x4*)(red_a + base);
#pragma unroll
        for (int j = 0; j < 4; ++j) h[j] = h0[j];
    }
    long tstep = dir ? -1 : 1;
    long row = (long)b * SEQ + (dir ? SEQ - 1 - c * CLEN : c * CLEN);
    float dlt = __bfloat162float(delta[row * DI + d]);
    float u   = __bfloat162float(xc[row * DI + d]);
    float zg  = __bfloat162float(z[row * DI + d]);
    f32x4 Bv  = *(const f32x4*)(dbl + row * 96 + 64 + sub * 4);
    f32x4 Cv  = *(const f32x4*)(dbl + row * 96 + 80 + sub * 4);
    for (int s = 0; s < CLEN; ++s) {
        long rown = row + tstep;
        float dltn = 0.f, un = 0.f, zgn = 0.f;
        f32x4 Bn = (f32x4){0.f,0.f,0.f,0.f}, Cn = (f32x4){0.f,0.f,0.f,0.f};
        if (s + 1 < CLEN) {
            dltn = __bfloat162float(delta[rown * DI + d]);
            un   = __bfloat162float(xc[rown * DI + d]);
            zgn  = __bfloat162float(z[rown * DI + d]);
            Bn   = *(const f32x4*)(dbl + rown * 96 + 64 + sub * 4);
            Cn   = *(const f32x4*)(dbl + rown * 96 + 80 + sub * 4);
        }
        float du = dlt * u;
        float y = 0.f;
#pragma unroll
        for (int j = 0; j < 4; ++j) {
            float dA = __expf(dlt * Ar[j]);
            h[j] = fmaf(h[j], dA, du * Bv[j]);
            y = fmaf(h[j], Cv[j], y);
        }
        y += __shfl_xor(y, 16, 64);
        y += __shfl_xor(y, 32, 64);
        if (sub == 0) {
            float yo = fmaf(u, Dd, y);
            xc[row * DI + d] = __float2bfloat16(yo * silu_f(zg));
        }
        row = rown; dlt = dltn; u = un; zg = zgn; Bv = Bn; Cv = Cn;
    }
}

extern "C" void kernel_launch(void* const* d_in, const int* in_sizes, int n_in,
                              void* d_out, int out_size, void* d_ws, size_t ws_size,
                              hipStream_t stream) {
    const float* x      = (const float*)d_in[0];
    const float* ln_g   = (const float*)d_in[1];
    const float* ln_b   = (const float*)d_in[2];
    const float* fus_w  = (const float*)d_in[3];
    const float* fus_b  = (const float*)d_in[4];
    const float* f_in_w = (const float*)d_in[5];
    const float* f_cw   = (const float*)d_in[6];
    const float* f_cb   = (const float*)d_in[7];
    const float* f_xpw  = (const float*)d_in[8];
    const float* f_dtw  = (const float*)d_in[9];
    const float* f_dtb  = (const float*)d_in[10];
    const float* f_Alog = (const float*)d_in[11];
    const float* f_D    = (const float*)d_in[12];
    const float* f_outw = (const float*)d_in[13];
    const float* b_in_w = (const float*)d_in[14];
    const float* b_cw   = (const float*)d_in[15];
    const float* b_cb   = (const float*)d_in[16];
    const float* b_xpw  = (const float*)d_in[17];
    const float* b_dtw  = (const float*)d_in[18];
    const float* b_dtb  = (const float*)d_in[19];
    const float* b_Alog = (const float*)d_in[20];
    const float* b_D    = (const float*)d_in[21];
    const float* b_outw = (const float*)d_in[22];
    float* out = (float*)d_out;

    char* w = (char*)d_ws;
    auto alloc = [&](size_t bytes) { char* p = w; w += (bytes + 255) & ~255UL; return p; };
    bf16* xn   = (bf16*)alloc((size_t)NTOK * DM * 2);
    bf16* xi_f = (bf16*)alloc((size_t)NTOK * DI * 2);
    bf16* xi_b = (bf16*)alloc((size_t)NTOK * DI * 2);
    bf16* z_f  = (bf16*)alloc((size_t)NTOK * DI * 2);
    bf16* z_b  = (bf16*)alloc((size_t)NTOK * DI * 2);
    bf16* xc_f = (bf16*)alloc((size_t)NTOK * DI * 2);
    bf16* xc_b = (bf16*)alloc((size_t)NTOK * DI * 2);
    bf16* feat = (bf16*)alloc((size_t)NTOK * 2 * DM * 2);
    float* dbl_f = (float*)alloc((size_t)NTOK * 96 * 4);
    float* dbl_b = (float*)alloc((size_t)NTOK * 96 * 4);
    bf16* w_fin  = (bf16*)alloc((size_t)2 * DI * DM * 2);
    bf16* w_bin  = (bf16*)alloc((size_t)2 * DI * DM * 2);
    bf16* w_fout = (bf16*)alloc((size_t)DM * DI * 2);
    bf16* w_bout = (bf16*)alloc((size_t)DM * DI * 2);
    bf16* w_fus  = (bf16*)alloc((size_t)DM * 2 * DM * 2);
    bf16* w_fxp  = (bf16*)alloc((size_t)96 * DI * 2);
    bf16* w_bxp  = (bf16*)alloc((size_t)96 * DI * 2);
    float* red_a = (float*)alloc((size_t)8 * CHUNKS * DI * 16 * 4);  // 16.8 MB
    float* red_b = (float*)alloc((size_t)8 * CHUNKS * DI * 16 * 4);
    bf16* delta_f = xi_f;      // alias: xi dead after conv
    bf16* delta_b = xi_b;

    // 0. weight conversion
    CvtArgs ca;
    ca.seg[0] = {f_in_w, w_fin,  2 * DI * DM};
    ca.seg[1] = {b_in_w, w_bin,  2 * DI * DM};
    ca.seg[2] = {f_outw, w_fout, DM * DI};
    ca.seg[3] = {b_outw, w_bout, DM * DI};
    ca.seg[4] = {fus_w,  w_fus,  DM * 2 * DM};
    ca.seg[5] = {f_xpw,  w_fxp,  96 * DI};
    ca.seg[6] = {b_xpw,  w_bxp,  96 * DI};
    cvt_kernel<<<dim3(4096, 7), 256, 0, stream>>>(ca);
    // 1. LayerNorm -> bf16
    ln_kernel<<<NTOK, 256, 0, stream>>>(x, ln_g, ln_b, xn);
    // 2. in-proj (batched z=4)
    {
        GB4 gb{};
        gb.p[0] = {xn, w_fin,                   xi_f};
        gb.p[1] = {xn, w_fin + (size_t)DI * DM, z_f};
        gb.p[2] = {xn, w_bin,                   xi_b};
        gb.p[3] = {xn, w_bin + (size_t)DI * DM, z_b};
        gemm_mfma<0, bf16><<<dim3(32, 16, 4), 256, 0, stream>>>(gb, DM, DM, DI, DI, DM,
                                                                nullptr, nullptr, 0);
    }
    // 3. depthwise conv + silu
    conv_kernel<<<2 * NTOK * (DI / 256), 256, 0, stream>>>(xi_f, xi_b, f_cw, f_cb,
                                                           b_cw, b_cb, xc_f, xc_b);
    // 4. x-proj (batched z=2): dbl (N=96, fp32 out)
    {
        GB4 gb{};
        gb.p[0] = {xc_f, w_fxp, dbl_f};
        gb.p[1] = {xc_b, w_bxp, dbl_b};
        gemm_mfma<0, float><<<dim3(32, 1, 2), 256, 0, stream>>>(gb, DI, DI, 96, 96, DI,
                                                                nullptr, nullptr, 0);
    }
    // 5. dt-proj + softplus -> bf16 delta
    gemm_nt<2, bf16><<<dim3(64, 32), 256, 0, stream>>>(dbl_f, 96, f_dtw, DTR,
                                                       delta_f, DI, DI, DTR, f_dtb);
    gemm_nt<2, bf16><<<dim3(64, 32), 256, 0, stream>>>(dbl_b, 96, b_dtw, DTR,
                                                       delta_b, DI, DI, DTR, b_dtb);
    // 6. chunked selective scan (3 passes)
    scan_reduce<<<4096, 256, 0, stream>>>(delta_f, delta_b, xc_f, xc_b,
                                          dbl_f, dbl_b, f_Alog, b_Alog, red_a, red_b);
    scan_combine<<<256, 256, 0, stream>>>(red_a, red_b);
    scan_apply<<<4096, 256, 0, stream>>>(delta_f, delta_b, xc_f, xc_b, z_f, z_b,
                                         dbl_f, dbl_b, f_Alog, b_Alog, f_D, b_D, red_a);
    // 7. out-proj (batched z=2) -> feat
    {
        GB4 gb{};
        gb.p[0] = {xc_f, w_fout, feat};
        gb.p[1] = {xc_b, w_bout, feat + DM};
        gemm_mfma<0, bf16><<<dim3(32, 8, 2), 256, 0, stream>>>(gb, DI, DI, 2 * DM, DM, DI,
                                                               nullptr, nullptr, 0);
    }
    // 8. fuse + bias + residual (fp32 out)
    {
        GB4 gb{};
        gb.p[0] = {feat, w_fus, out};
        gemm_mfma<3, float><<<dim3(32, 8, 1), 256, 0, stream>>>(gb, 2 * DM, 2 * DM, DM,
                                                                DM, 2 * DM, fus_b, x, DM);
    }
}

// Round 5
// 712.543 us; speedup vs baseline: 3.8296x; 1.0603x over previous
//
#include <hip/hip_runtime.h>
#include <hip/hip_bf16.h>
#include <math.h>

#define B_SZ 4
#define SEQ  1024
#define DM   1024
#define DI   2048
#define DTR  64
#define DS   16
#define NTOK (B_SZ*SEQ)   /* 4096 tokens */
#define CHUNKS 16
#define CLEN   64         /* SEQ / CHUNKS */

typedef __hip_bfloat16 bf16;
typedef short bf16x8 __attribute__((ext_vector_type(8)));
typedef float f32x4  __attribute__((ext_vector_type(4)));
typedef unsigned int u32;

__device__ __forceinline__ float silu_f(float x) { return x / (1.f + __expf(-x)); }
__device__ __forceinline__ float softplus_f(float x) {
    return fmaxf(x, 0.f) + log1pf(__expf(-fabsf(x)));
}
__device__ __forceinline__ void stv(float* p, float v) { *p = v; }
__device__ __forceinline__ void stv(bf16* p, float v)  { *p = __float2bfloat16(v); }
__device__ __forceinline__ unsigned short bfbits(float f) {
    union { bf16 h; unsigned short u; } c; c.h = __float2bfloat16(f); return c.u;
}
__device__ __forceinline__ float bf2f(short s) {
    union { float f; unsigned u; } c; c.u = ((unsigned)(unsigned short)s) << 16; return c.f;
}
// async 16B/lane global->LDS DMA; LDS dest = base + lane*16 (wave-uniform base)
__device__ __forceinline__ void async_cp16(const void* g, void* l) {
    __builtin_amdgcn_global_load_lds((const __attribute__((address_space(1))) u32*)g,
                                     (__attribute__((address_space(3))) u32*)l, 16, 0, 0);
}

// ---------------- fp32 -> bf16 weight conversion (7 segments, one launch) ----------
struct CvtSeg { const float* s; bf16* d; int n; };
struct CvtArgs { CvtSeg seg[7]; };
__global__ __launch_bounds__(256) void cvt_kernel(CvtArgs a) {
    CvtSeg sg = a.seg[blockIdx.y];
    int base = (blockIdx.x * 256 + threadIdx.x) * 4;
    if (base >= sg.n) return;
    float4 v = *(const float4*)(sg.s + base);
    ushort4 o;
    o.x = bfbits(v.x); o.y = bfbits(v.y); o.z = bfbits(v.z); o.w = bfbits(v.w);
    *(ushort4*)(sg.d + base) = o;
}

// ---------------- LayerNorm over last dim (1024), bf16 out ----------------
__global__ __launch_bounds__(256) void ln_kernel(const float* __restrict__ x,
                                                 const float* __restrict__ g,
                                                 const float* __restrict__ be,
                                                 bf16* __restrict__ xn) {
    int row = blockIdx.x;
    const float* xr = x + (long)row * DM;
    float v[4];
    float s = 0.f, ss = 0.f;
#pragma unroll
    for (int i = 0; i < 4; ++i) {
        v[i] = xr[threadIdx.x + 256 * i];
        s += v[i]; ss += v[i] * v[i];
    }
#pragma unroll
    for (int off = 32; off >= 1; off >>= 1) {
        s  += __shfl_xor(s, off, 64);
        ss += __shfl_xor(ss, off, 64);
    }
    __shared__ float sh[8];
    int wid = threadIdx.x >> 6;
    if ((threadIdx.x & 63) == 0) { sh[wid] = s; sh[4 + wid] = ss; }
    __syncthreads();
    s  = sh[0] + sh[1] + sh[2] + sh[3];
    ss = sh[4] + sh[5] + sh[6] + sh[7];
    float mu  = s / DM;
    float var = ss / DM - mu * mu;
    float rs  = rsqrtf(var + 1e-5f);
    bf16* xo = xn + (long)row * DM;
#pragma unroll
    for (int i = 0; i < 4; ++i) {
        int c = threadIdx.x + 256 * i;
        xo[c] = __float2bfloat16((v[i] - mu) * rs * g[c] + be[c]);
    }
}

// ---------------- bf16 MFMA GEMM (m97-style global_load_lds staging) ----------------
// C[m,n] = sum_k A[m,k]*B[n,k]; 128x128 tile, BK=32, 256 thr = 2x2 waves of 64x64.
struct GPtr { const bf16* A; const bf16* B; void* C; };
struct GB4 { GPtr p[4]; };

template <int EPI, typename OutT>   // EPI: 0 none, 1 +bias, 3 +bias+resid
__global__ __launch_bounds__(256) void gemm_mfma(GB4 gb, int lda, int ldb, int ldc,
                                                 int N, int K,
                                                 const float* __restrict__ bias,
                                                 const float* __restrict__ resid, int ldr) {
    __shared__ __align__(16) short As[128 * 32];   // identity layout [row][32k]
    __shared__ __align__(16) short Bs[128 * 32];
    GPtr g = gb.p[blockIdx.z];
    const short* A = (const short*)g.A;
    const short* B = (const short*)g.B;
    OutT* C = (OutT*)g.C;
    const int tid = threadIdx.x;
    const int m0 = blockIdx.x * 128, n0 = blockIdx.y * 128;
    const int lane = tid & 63, wv = tid >> 6;
    const int wm = (wv >> 1) * 64, wn = (wv & 1) * 64;
    // staging: wave wv covers tile rows [wv*32, wv*32+32), 2 DMA insts per buffer
    const int srow = wv * 32 + (lane >> 2);
    const int sq   = (lane & 3) * 8;               // bf16 offset (16B chunk)
    const short* pa0 = A + (long)(m0 + srow) * lda + sq;
    const short* pa1 = pa0 + 16 * lda;
    int rb0 = n0 + srow;      rb0 = rb0 < N ? rb0 : N - 1;
    int rb1 = n0 + srow + 16; rb1 = rb1 < N ? rb1 : N - 1;
    const short* pb0 = B + (long)rb0 * ldb + sq;
    const short* pb1 = B + (long)rb1 * ldb + sq;
    short* la0 = &As[(wv * 32) * 32];
    short* la1 = &As[(wv * 32 + 16) * 32];
    short* lb0 = &Bs[(wv * 32) * 32];
    short* lb1 = &Bs[(wv * 32 + 16) * 32];
    f32x4 acc[4][4];
#pragma unroll
    for (int i = 0; i < 4; ++i)
#pragma unroll
        for (int j = 0; j < 4; ++j) acc[i][j] = (f32x4){0.f, 0.f, 0.f, 0.f};

    for (int k0 = 0; k0 < K; k0 += 32) {
        __syncthreads();                       // prev-iter frag reads done
        async_cp16(pa0 + k0, la0);
        async_cp16(pa1 + k0, la1);
        async_cp16(pb0 + k0, lb0);
        async_cp16(pb1 + k0, lb1);
        __syncthreads();                       // vmcnt drain -> LDS valid
        bf16x8 af[4], bfr[4];
#pragma unroll
        for (int t = 0; t < 4; ++t) {
            int ra = wm + t * 16 + (lane & 15);
            af[t]  = *(const bf16x8*)&As[ra * 32 + (lane >> 4) * 8];
            int rb = wn + t * 16 + (lane & 15);
            bfr[t] = *(const bf16x8*)&Bs[rb * 32 + (lane >> 4) * 8];
        }
#pragma unroll
        for (int i = 0; i < 4; ++i)
#pragma unroll
            for (int j = 0; j < 4; ++j)
                acc[i][j] = __builtin_amdgcn_mfma_f32_16x16x32_bf16(af[i], bfr[j], acc[i][j], 0, 0, 0);
    }
#pragma unroll
    for (int i = 0; i < 4; ++i) {
        int rowb = m0 + wm + i * 16 + ((lane >> 4) << 2);
#pragma unroll
        for (int j = 0; j < 4; ++j) {
            int col = n0 + wn + j * 16 + (lane & 15);
            if (col < N) {
#pragma unroll
                for (int rr = 0; rr < 4; ++rr) {
                    float v = acc[i][j][rr];
                    if (EPI >= 1) v += bias[col];
                    if (EPI == 3) v += resid[(long)(rowb + rr) * ldr + col];
                    stv(&C[(long)(rowb + rr) * ldc + col], v);
                }
            }
        }
    }
}

// ---------------- fp32 vector GEMM (dt-proj only): C = A @ B.T ----------------
template <int EPI, typename OutT>   // EPI: 2 = softplus(acc+bias)
__global__ __launch_bounds__(256) void gemm_nt(const float* __restrict__ A, int lda,
                                               const float* __restrict__ B, int ldb,
                                               OutT* __restrict__ C, int ldc,
                                               int N, int K,
                                               const float* __restrict__ bias) {
    __shared__ __align__(16) float As[16][68];
    __shared__ __align__(16) float Bs[16][68];
    const int tid = threadIdx.x;
    const int m0  = blockIdx.x * 64;
    const int n0  = blockIdx.y * 64;
    const int lr  = tid >> 2;
    const int lc  = (tid & 3) << 2;
    const int ty  = tid >> 4;
    const int tx  = tid & 15;
    float acc[4][4] = {};
    const float* ap0 = A + (long)(m0 + lr) * lda + lc;
    const float* bp0 = B + (long)(n0 + lr) * ldb + lc;
    for (int k0 = 0; k0 < K; k0 += 16) {
        float4 av = *(const float4*)(ap0 + k0);
        float4 bv = *(const float4*)(bp0 + k0);
        __syncthreads();
        As[lc + 0][lr] = av.x; As[lc + 1][lr] = av.y; As[lc + 2][lr] = av.z; As[lc + 3][lr] = av.w;
        Bs[lc + 0][lr] = bv.x; Bs[lc + 1][lr] = bv.y; Bs[lc + 2][lr] = bv.z; Bs[lc + 3][lr] = bv.w;
        __syncthreads();
#pragma unroll
        for (int kk = 0; kk < 16; ++kk) {
            float4 a4 = *(const float4*)&As[kk][ty << 2];
            float4 b4 = *(const float4*)&Bs[kk][tx << 2];
            float a[4] = {a4.x, a4.y, a4.z, a4.w};
            float b[4] = {b4.x, b4.y, b4.z, b4.w};
#pragma unroll
            for (int i = 0; i < 4; ++i)
#pragma unroll
                for (int j = 0; j < 4; ++j)
                    acc[i][j] = fmaf(a[i], b[j], acc[i][j]);
        }
    }
#pragma unroll
    for (int i = 0; i < 4; ++i) {
        int m = m0 + (ty << 2) + i;
#pragma unroll
        for (int j = 0; j < 4; ++j) {
            int n = n0 + (tx << 2) + j;
            float v = acc[i][j];
            if (EPI >= 1) v += bias[n];
            if (EPI == 2) v = softplus_f(v);
            stv(&C[(long)m * ldc + n], v);
        }
    }
}

// ---------------- Depthwise causal conv (window 4) + SiLU, 8 channels/thread -------
__global__ __launch_bounds__(256) void conv_kernel(const bf16* __restrict__ xi_f,
                                                   const bf16* __restrict__ xi_b,
                                                   const float* __restrict__ wf,
                                                   const float* __restrict__ bfs,
                                                   const float* __restrict__ wb,
                                                   const float* __restrict__ bb,
                                                   bf16* __restrict__ xc_f,
                                                   bf16* __restrict__ xc_b) {
    long idx = (long)blockIdx.x * 256 + threadIdx.x;
    const long per = (long)NTOK * (DI / 8);
    int dir = idx >= per;
    long i  = dir ? idx - per : idx;
    int  d8 = (int)(i & 255) * 8;
    long tok = i >> 8;
    int  l  = (int)(tok & (SEQ - 1));
    const float* w    = dir ? wb : wf;
    const float* bias = dir ? bb : bfs;
    const bf16* xi = (dir ? xi_b : xi_f) + tok * DI + d8;
    float acc[8], wreg[8][4];
#pragma unroll
    for (int j = 0; j < 8; ++j) {
        acc[j] = bias[d8 + j];
        f32x4 wv = *(const f32x4*)(w + (d8 + j) * 4);
        wreg[j][0] = wv[0]; wreg[j][1] = wv[1]; wreg[j][2] = wv[2]; wreg[j][3] = wv[3];
    }
#pragma unroll
    for (int k = 0; k < 4; ++k) {
        int lp = dir ? (l + 3 - k) : (l - 3 + k);
        if (lp >= 0 && lp < SEQ) {
            bf16x8 v = *(const bf16x8*)(xi + (long)(lp - l) * DI);
#pragma unroll
            for (int j = 0; j < 8; ++j) acc[j] = fmaf(wreg[j][k], bf2f(v[j]), acc[j]);
        }
    }
    bf16x8 o;
#pragma unroll
    for (int j = 0; j < 8; ++j) o[j] = (short)bfbits(silu_f(acc[j]));
    *(bf16x8*)((dir ? xc_b : xc_f) + tok * DI + d8) = o;
}

// =========== Chunked selective scan: one lane owns one channel (16 states) ==========
// blocks: dir(2) x b(4) x c(16) x dgrp(8) = 1024; d = dg*256 + tid. Chunk c covers
// scan steps s in [0,64), token t = dir ? SEQ-1-c*64-s : c*64+s. B (and C in apply)
// staged per-chunk into LDS in scan order. red_a/red_b layout:
// (((dir*4+b)*CHUNKS+c)*DI + d)*16 + state. combine rewrites red_a with h_init.

__global__ __launch_bounds__(256) void scan_reduce(
        const bf16* __restrict__ delta_f, const bf16* __restrict__ delta_b,
        const bf16* __restrict__ xc_f, const bf16* __restrict__ xc_b,
        const float* __restrict__ dbl_f, const float* __restrict__ dbl_b,
        const float* __restrict__ Alog_f, const float* __restrict__ Alog_b,
        float* __restrict__ red_a, float* __restrict__ red_b) {
    int blk = blockIdx.x;
    int dg  = blk & 7;
    int c   = (blk >> 3) & 15;
    int b   = (blk >> 7) & 3;
    int dir = blk >> 9;
    int d   = dg * 256 + threadIdx.x;
    const bf16* delta = dir ? delta_b : delta_f;
    const bf16* xc    = dir ? xc_b : xc_f;
    const float* dbl  = dir ? dbl_b : dbl_f;
    const float* Alog = (dir ? Alog_b : Alog_f) + d * DS;
    __shared__ float Bsh[CLEN * 16];
    {
        int r = threadIdx.x >> 2, q = threadIdx.x & 3;
        long grow = (long)b * SEQ + (dir ? (SEQ - 1 - c * CLEN - r) : (c * CLEN + r));
        *(f32x4*)&Bsh[r * 16 + q * 4] = *(const f32x4*)(dbl + grow * 96 + 64 + q * 4);
    }
    __syncthreads();
    float Ar2[DS], aprod[DS], bacc[DS];
#pragma unroll
    for (int j = 0; j < DS; ++j) {
        Ar2[j] = -__expf(Alog[j]) * 1.44269504089f;   // pre-scale: exp(x)=exp2(x*log2e)
        aprod[j] = 1.f; bacc[j] = 0.f;
    }
    long tstep = dir ? -1 : 1;
    long row = (long)b * SEQ + (dir ? SEQ - 1 - c * CLEN : c * CLEN);
    float dlt = __bfloat162float(delta[row * DI + d]);
    float u   = __bfloat162float(xc[row * DI + d]);
    for (int s = 0; s < CLEN; ++s) {
        long rown = row + tstep;
        float dltn = 0.f, un = 0.f;
        if (s + 1 < CLEN) {
            dltn = __bfloat162float(delta[rown * DI + d]);
            un   = __bfloat162float(xc[rown * DI + d]);
        }
        float du = dlt * u;
#pragma unroll
        for (int q = 0; q < 4; ++q) {
            f32x4 Bq = *(const f32x4*)&Bsh[s * 16 + q * 4];
#pragma unroll
            for (int j = 0; j < 4; ++j) {
                int ix = q * 4 + j;
                float dA = exp2f(dlt * Ar2[ix]);
                bacc[ix]  = fmaf(bacc[ix], dA, du * Bq[j]);
                aprod[ix] *= dA;
            }
        }
        row = rown; dlt = dltn; u = un;
    }
    long base = (((long)(dir * 4 + b) * CHUNKS + c) * DI + d) * 16;
#pragma unroll
    for (int q = 0; q < 4; ++q) {
        *(f32x4*)(red_a + base + q * 4) =
            (f32x4){aprod[q*4], aprod[q*4+1], aprod[q*4+2], aprod[q*4+3]};
        *(f32x4*)(red_b + base + q * 4) =
            (f32x4){bacc[q*4], bacc[q*4+1], bacc[q*4+2], bacc[q*4+3]};
    }
}

__global__ __launch_bounds__(256) void scan_combine(float* __restrict__ red_a,
                                                    const float* __restrict__ red_b) {
    int tid = blockIdx.x * 256 + threadIdx.x;   // 65536 threads: (dir,b,d,sub)
    int sub = tid & 3;
    int d   = (tid >> 2) & 2047;
    int db  = tid >> 13;
    f32x4 h = (f32x4){0.f, 0.f, 0.f, 0.f};
    for (int c = 0; c < CHUNKS; ++c) {
        long idx = (((long)db * CHUNKS + c) * DI + d) * 16 + sub * 4;
        f32x4 a = *(const f32x4*)(red_a + idx);
        f32x4 w = *(const f32x4*)(red_b + idx);
        *(f32x4*)(red_a + idx) = h;
#pragma unroll
        for (int j = 0; j < 4; ++j) h[j] = fmaf(a[j], h[j], w[j]);
    }
}

__global__ __launch_bounds__(256) void scan_apply(
        const bf16* __restrict__ delta_f, const bf16* __restrict__ delta_b,
        bf16* __restrict__ xc_f, bf16* __restrict__ xc_b,
        const bf16* __restrict__ z_f, const bf16* __restrict__ z_b,
        const float* __restrict__ dbl_f, const float* __restrict__ dbl_b,
        const float* __restrict__ Alog_f, const float* __restrict__ Alog_b,
        const float* __restrict__ Df, const float* __restrict__ Db,
        const float* __restrict__ red_a) {
    int blk = blockIdx.x;
    int dg  = blk & 7;
    int c   = (blk >> 3) & 15;
    int b   = (blk >> 7) & 3;
    int dir = blk >> 9;
    int d   = dg * 256 + threadIdx.x;
    const bf16* delta = dir ? delta_b : delta_f;
    bf16*       xc    = dir ? xc_b : xc_f;
    const bf16* z     = dir ? z_b : z_f;
    const float* dbl  = dir ? dbl_b : dbl_f;
    const float* Alog = (dir ? Alog_b : Alog_f) + d * DS;
    float Dd = (dir ? Db : Df)[d];
    __shared__ float BCsh[CLEN * 32];    // [step][0:16)=B, [16:32)=C
#pragma unroll
    for (int it = 0; it < 2; ++it) {
        int i = it * 256 + threadIdx.x;
        int r = i >> 3, q = i & 7;
        long grow = (long)b * SEQ + (dir ? (SEQ - 1 - c * CLEN - r) : (c * CLEN + r));
        *(f32x4*)&BCsh[r * 32 + q * 4] = *(const f32x4*)(dbl + grow * 96 + 64 + q * 4);
    }
    __syncthreads();
    float Ar2[DS], h[DS];
#pragma unroll
    for (int j = 0; j < DS; ++j) Ar2[j] = -__expf(Alog[j]) * 1.44269504089f;
    {
        long base = (((long)(dir * 4 + b) * CHUNKS + c) * DI + d) * 16;
#pragma unroll
        for (int q = 0; q < 4; ++q) {
            f32x4 h0 = *(const f32x4*)(red_a + base + q * 4);
            h[q*4] = h0[0]; h[q*4+1] = h0[1]; h[q*4+2] = h0[2]; h[q*4+3] = h0[3];
        }
    }
    long tstep = dir ? -1 : 1;
    long row = (long)b * SEQ + (dir ? SEQ - 1 - c * CLEN : c * CLEN);
    float dlt = __bfloat162float(delta[row * DI + d]);
    float u   = __bfloat162float(xc[row * DI + d]);
    float zg  = __bfloat162float(z[row * DI + d]);
    for (int s = 0; s < CLEN; ++s) {
        long rown = row + tstep;
        float dltn = 0.f, un = 0.f, zgn = 0.f;
        if (s + 1 < CLEN) {
            dltn = __bfloat162float(delta[rown * DI + d]);
            un   = __bfloat162float(xc[rown * DI + d]);
            zgn  = __bfloat162float(z[rown * DI + d]);
        }
        float du = dlt * u;
        float y = 0.f;
#pragma unroll
        for (int q = 0; q < 4; ++q) {
            f32x4 Bq = *(const f32x4*)&BCsh[s * 32 + q * 4];
            f32x4 Cq = *(const f32x4*)&BCsh[s * 32 + 16 + q * 4];
#pragma unroll
            for (int j = 0; j < 4; ++j) {
                int ix = q * 4 + j;
                float dA = exp2f(dlt * Ar2[ix]);
                h[ix] = fmaf(h[ix], dA, du * Bq[j]);
                y = fmaf(h[ix], Cq[j], y);
            }
        }
        float yo = fmaf(u, Dd, y);
        xc[row * DI + d] = __float2bfloat16(yo * silu_f(zg));
        row = rown; dlt = dltn; u = un; zg = zgn;
    }
}

extern "C" void kernel_launch(void* const* d_in, const int* in_sizes, int n_in,
                              void* d_out, int out_size, void* d_ws, size_t ws_size,
                              hipStream_t stream) {
    const float* x      = (const float*)d_in[0];
    const float* ln_g   = (const float*)d_in[1];
    const float* ln_b   = (const float*)d_in[2];
    const float* fus_w  = (const float*)d_in[3];
    const float* fus_b  = (const float*)d_in[4];
    const float* f_in_w = (const float*)d_in[5];
    const float* f_cw   = (const float*)d_in[6];
    const float* f_cb   = (const float*)d_in[7];
    const float* f_xpw  = (const float*)d_in[8];
    const float* f_dtw  = (const float*)d_in[9];
    const float* f_dtb  = (const float*)d_in[10];
    const float* f_Alog = (const float*)d_in[11];
    const float* f_D    = (const float*)d_in[12];
    const float* f_outw = (const float*)d_in[13];
    const float* b_in_w = (const float*)d_in[14];
    const float* b_cw   = (const float*)d_in[15];
    const float* b_cb   = (const float*)d_in[16];
    const float* b_xpw  = (const float*)d_in[17];
    const float* b_dtw  = (const float*)d_in[18];
    const float* b_dtb  = (const float*)d_in[19];
    const float* b_Alog = (const float*)d_in[20];
    const float* b_D    = (const float*)d_in[21];
    const float* b_outw = (const float*)d_in[22];
    float* out = (float*)d_out;

    char* w = (char*)d_ws;
    auto alloc = [&](size_t bytes) { char* p = w; w += (bytes + 255) & ~255UL; return p; };
    bf16* xn   = (bf16*)alloc((size_t)NTOK * DM * 2);
    bf16* xi_f = (bf16*)alloc((size_t)NTOK * DI * 2);
    bf16* xi_b = (bf16*)alloc((size_t)NTOK * DI * 2);
    bf16* z_f  = (bf16*)alloc((size_t)NTOK * DI * 2);
    bf16* z_b  = (bf16*)alloc((size_t)NTOK * DI * 2);
    bf16* xc_f = (bf16*)alloc((size_t)NTOK * DI * 2);
    bf16* xc_b = (bf16*)alloc((size_t)NTOK * DI * 2);
    bf16* feat = (bf16*)alloc((size_t)NTOK * 2 * DM * 2);
    float* dbl_f = (float*)alloc((size_t)NTOK * 96 * 4);
    float* dbl_b = (float*)alloc((size_t)NTOK * 96 * 4);
    bf16* w_fin  = (bf16*)alloc((size_t)2 * DI * DM * 2);
    bf16* w_bin  = (bf16*)alloc((size_t)2 * DI * DM * 2);
    bf16* w_fout = (bf16*)alloc((size_t)DM * DI * 2);
    bf16* w_bout = (bf16*)alloc((size_t)DM * DI * 2);
    bf16* w_fus  = (bf16*)alloc((size_t)DM * 2 * DM * 2);
    bf16* w_fxp  = (bf16*)alloc((size_t)96 * DI * 2);
    bf16* w_bxp  = (bf16*)alloc((size_t)96 * DI * 2);
    float* red_a = (float*)alloc((size_t)8 * CHUNKS * DI * 16 * 4);
    float* red_b = (float*)alloc((size_t)8 * CHUNKS * DI * 16 * 4);
    bf16* delta_f = xi_f;      // alias: xi dead after conv
    bf16* delta_b = xi_b;

    // 0. weight conversion
    CvtArgs ca;
    ca.seg[0] = {f_in_w, w_fin,  2 * DI * DM};
    ca.seg[1] = {b_in_w, w_bin,  2 * DI * DM};
    ca.seg[2] = {f_outw, w_fout, DM * DI};
    ca.seg[3] = {b_outw, w_bout, DM * DI};
    ca.seg[4] = {fus_w,  w_fus,  DM * 2 * DM};
    ca.seg[5] = {f_xpw,  w_fxp,  96 * DI};
    ca.seg[6] = {b_xpw,  w_bxp,  96 * DI};
    cvt_kernel<<<dim3(4096, 7), 256, 0, stream>>>(ca);
    // 1. LayerNorm -> bf16
    ln_kernel<<<NTOK, 256, 0, stream>>>(x, ln_g, ln_b, xn);
    // 2. in-proj (batched z=4)
    {
        GB4 gb{};
        gb.p[0] = {xn, w_fin,                   xi_f};
        gb.p[1] = {xn, w_fin + (size_t)DI * DM, z_f};
        gb.p[2] = {xn, w_bin,                   xi_b};
        gb.p[3] = {xn, w_bin + (size_t)DI * DM, z_b};
        gemm_mfma<0, bf16><<<dim3(32, 16, 4), 256, 0, stream>>>(gb, DM, DM, DI, DI, DM,
                                                                nullptr, nullptr, 0);
    }
    // 3. depthwise conv + silu (8 ch/thread)
    conv_kernel<<<2 * NTOK, 256, 0, stream>>>(xi_f, xi_b, f_cw, f_cb,
                                              b_cw, b_cb, xc_f, xc_b);
    // 4. x-proj (batched z=2): dbl (N=96, fp32 out)
    {
        GB4 gb{};
        gb.p[0] = {xc_f, w_fxp, dbl_f};
        gb.p[1] = {xc_b, w_bxp, dbl_b};
        gemm_mfma<0, float><<<dim3(32, 1, 2), 256, 0, stream>>>(gb, DI, DI, 96, 96, DI,
                                                                nullptr, nullptr, 0);
    }
    // 5. dt-proj + softplus -> bf16 delta
    gemm_nt<2, bf16><<<dim3(64, 32), 256, 0, stream>>>(dbl_f, 96, f_dtw, DTR,
                                                       delta_f, DI, DI, DTR, f_dtb);
    gemm_nt<2, bf16><<<dim3(64, 32), 256, 0, stream>>>(dbl_b, 96, b_dtw, DTR,
                                                       delta_b, DI, DI, DTR, b_dtb);
    // 6. chunked selective scan (3 passes)
    scan_reduce<<<1024, 256, 0, stream>>>(delta_f, delta_b, xc_f, xc_b,
                                          dbl_f, dbl_b, f_Alog, b_Alog, red_a, red_b);
    scan_combine<<<256, 256, 0, stream>>>(red_a, red_b);
    scan_apply<<<1024, 256, 0, stream>>>(delta_f, delta_b, xc_f, xc_b, z_f, z_b,
                                         dbl_f, dbl_b, f_Alog, b_Alog, f_D, b_D, red_a);
    // 7. out-proj (batched z=2) -> feat
    {
        GB4 gb{};
        gb.p[0] = {xc_f, w_fout, feat};
        gb.p[1] = {xc_b, w_bout, feat + DM};
        gemm_mfma<0, bf16><<<dim3(32, 8, 2), 256, 0, stream>>>(gb, DI, DI, 2 * DM, DM, DI,
                                                               nullptr, nullptr, 0);
    }
    // 8. fuse + bias + residual (fp32 out)
    {
        GB4 gb{};
        gb.p[0] = {feat, w_fus, out};
        gemm_mfma<3, float><<<dim3(32, 8, 1), 256, 0, stream>>>(gb, 2 * DM, 2 * DM, DM,
                                                                DM, 2 * DM, fus_b, x, DM);
    }
}